// Round 5
// baseline (9899.477 us; speedup 1.0000x reference)
//
#include <hip/hip_runtime.h>
#include <stdint.h>

// LSTM: B=256, T=1024, I=64, H=256, O=1. fp32 in/out, bf16 MFMA internally.
//
// Round-16 = R15 topology (64 blocks = 32 groups x 2 halves, 512 thr) with
// the two fixes the R15 counters demand:
//  (1) __launch_bounds__(512,1): R15's (512,2) made the allocator cap VGPRs
//      at 128 (VGPR_Count=128 in rocprof), spilling the entire wf[4][10]
//      weight array to scratch and re-reading it every K-step (~+2000
//      cy/step, the whole 3120us regression). Cap 512 keeps ~240 resident.
//  (2) software-pipelined recurrence: gates = W_x x + W_own h_own +
//      W_peer h_peer. Phase A (bias + x-part + OWN-half h: 24 MFMAs) runs
//      while the peer poll is in flight (first probe issued before Phase
//      A). Only Phase C (peer-half: 16 MFMAs) + nonlin + publish sit inside
//      the serial publish->visibility->detect cycle. Critical path per step
//      ~5200 -> ~1500 cy.
// x is prefetched one step ahead (clamped at T-1) so its latency hides
// under Phase A + poll.
//
// Communication: R11/R13-verified relaxed AGENT-scope (MALL) 8B units
// {2xbf16 h pair, tag=step}; quiet pipelined poll (probe before sleep,
// reload issued BEFORE s_sleep(1), satisfied lanes stop loading, SENT_CAP
// dead-latch => wrong-answer-not-hang). Tag poison 0xAAAAAAAA != live tags
// 1..1024 => no ws init. Final h (tag 1024) -> separate never-polled clean
// region at 2*UPP (R13-verified); parity/staleness argument as R15.
//
// LDS: h_lds[2][8][264] double buffer. iter t: Phase A reads OWN cols of
// buf[t&1] (written by update(t-1), ordered by end-barrier(t-1)); capture
// writes PEER cols of buf[t&1] (disjoint); MID-barrier; Phase C reads peer
// cols; update writes own h(t+1) to buf[(t+1)&1] + publishes; END-barrier.
// Buf reuse distance 2 steps, all hazards barrier-ordered.
//
// Unit index in group: half*512 + m*64 + pair (pair = local hid/2).
// Wave wv owns hid_local = wv*16 + ln for ALL 4 gates; c/h update fully
// in-register (lanes lk<2 hold C rows m = lk*4 + r).

#define T_ 1024
#define I_ 64
#define H_ 256
#define NGROUP 32
#define MB 8      /* batches per group  */
#define HH 128    /* hidden units per block (half) */
#define HROW 264  /* padded h_lds row (ushorts), 528 B = 33 x 16 B */

#define UNITS_PER_GROUP 1024                       /* 8B units per step */
#define UNITS_PER_PARITY (NGROUP * UNITS_PER_GROUP)
#define SENT_CAP (1 << 16)   /* dead-latch: ~64k sleep-sweeps */

typedef float floatx4 __attribute__((ext_vector_type(4)));
typedef __bf16 bf16x8 __attribute__((ext_vector_type(8)));
typedef unsigned short ushortx8 __attribute__((ext_vector_type(8)));
typedef unsigned int uint32;
typedef unsigned long long u64;

__device__ __forceinline__ float bf2f(uint32 u16) {
  uint32 u = u16 << 16;
  return __builtin_bit_cast(float, u);
}
__device__ __forceinline__ bf16x8 packbf8(floatx4 a, floatx4 b) {
  bf16x8 r;
  r[0] = (__bf16)a[0]; r[1] = (__bf16)a[1];
  r[2] = (__bf16)a[2]; r[3] = (__bf16)a[3];
  r[4] = (__bf16)b[0]; r[5] = (__bf16)b[1];
  r[6] = (__bf16)b[2]; r[7] = (__bf16)b[3];
  return r;
}
__device__ __forceinline__ float fast_sig(float v) {
  return 1.0f / (1.0f + __expf(-v));
}
__device__ __forceinline__ float fast_tanh(float v) {
  float e = __expf(2.0f * v);
  return 1.0f - 2.0f / (e + 1.0f);
}
__device__ __forceinline__ u64 aload64(const u64* p) {
  return __hip_atomic_load(p, __ATOMIC_RELAXED, __HIP_MEMORY_SCOPE_AGENT);
}
__device__ __forceinline__ void astore64(u64* p, u64 v) {
  __hip_atomic_store(p, v, __ATOMIC_RELAXED, __HIP_MEMORY_SCOPE_AGENT);
}

__global__ __launch_bounds__(512, 1) void lstm_main(
    const float* __restrict__ x, const float* __restrict__ W_ih,
    const float* __restrict__ W_hh, const float* __restrict__ b_ih,
    const float* __restrict__ b_hh, u64* __restrict__ units) {
  const int tid = threadIdx.x;
  const int bid = blockIdx.x;
  const int half = bid >> 5;  // 0..1
  const int g = bid & 31;     // group 0..31 (bid%8 spreads XCDs)
  const int wv = tid >> 6;    // wave 0..7 -> hid sub-block
  const int lane = tid & 63;
  const int ln = lane & 15;   // MFMA n (hid) / A row (batch, dup)
  const int lk = lane >> 4;   // MFMA k-subgroup / C row group

  __shared__ __align__(16) unsigned short h_lds[2][MB][HROW];

  const size_t gbase = (size_t)g * UNITS_PER_GROUP;
  const size_t obase = gbase + (size_t)half * 512;        // own units
  const size_t pbase = gbase + (size_t)(half ^ 1) * 512;  // peer units

  // zero both h_lds buffers (h_0 = 0; also clears pad)
  {
    uint32* p = (uint32*)&h_lds[0][0][0];
    for (int i = tid; i < 2 * MB * HROW / 2; i += 512) p[i] = 0u;
  }

  // ---- preload weight B-fragments (bf16) + bias, once ----
  // wave wv owns hid = half*128 + wv*16 + ln, ALL 4 gates (j).
  bf16x8 wf[4][10];
  float bias[4];
#pragma unroll
  for (int j = 0; j < 4; ++j) {
    const int row = j * 256 + half * HH + wv * 16 + ln;
    bias[j] = b_ih[row] + b_hh[row];
#pragma unroll
    for (int kc = 0; kc < 10; ++kc) {
      const int kk = kc * 32 + lk * 8;
      const float* src = (kk < I_) ? (W_ih + (size_t)row * I_ + kk)
                                   : (W_hh + (size_t)row * H_ + (kk - I_));
      floatx4 f0 = *(const floatx4*)src;
      floatx4 f1 = *(const floatx4*)(src + 4);
      wf[j][kc] = packbf8(f0, f1);
    }
  }

  const int mb = ln & 7;                       // batch row (m>=8 duplicates)
  const float* xrow = x + ((size_t)(g * MB + mb)) * T_ * I_;
  // poll roles: thread i <-> peer unit i
  const int pm = tid >> 6;                     // batch of polled unit
  const int pcol = (half ^ 1) * HH + 2 * (tid & 63);  // h_lds col (ushort)
  // publish roles: active lanes lk<2 && even ln; pair idx within half
  const int ppair = wv * 8 + (ln >> 1);
  const int ocol = half * HH + wv * 16 + ln;   // own h_lds col (ushort)
  // kc split: own-half h lives at kc 2+half*4 .. +3; peer at 2+(half^1)*4
  const int kcO = 2 + half * 4;
  const int kcP = 2 + (half ^ 1) * 4;

  floatx4 c_reg = (floatx4){0.f, 0.f, 0.f, 0.f};

  // preload x_0
  floatx4 xf0, xf1, xf2, xf3;
  {
    const float* src = xrow + lk * 8;
    xf0 = *(const floatx4*)(src);
    xf1 = *(const floatx4*)(src + 4);
    xf2 = *(const floatx4*)(src + 32);
    xf3 = *(const floatx4*)(src + 36);
  }

  __syncthreads();

#pragma unroll 1
  for (int t = 0; t < T_; ++t) {
    // pack x_t fragments, then issue x_{t+1} prefetch (latency hides under
    // Phase A + poll)
    bf16x8 a0 = packbf8(xf0, xf1);
    bf16x8 a1 = packbf8(xf2, xf3);
    {
      const int tn = (t + 1 < T_) ? (t + 1) : t;
      const float* src = xrow + tn * I_ + lk * 8;
      xf0 = *(const floatx4*)(src);
      xf1 = *(const floatx4*)(src + 4);
      xf2 = *(const floatx4*)(src + 32);
      xf3 = *(const floatx4*)(src + 36);
    }

    // issue first poll probe BEFORE Phase A so it flies under the MFMAs
    u64* up = units + (size_t)(t & 1) * UNITS_PER_PARITY + pbase + tid;
    u64 v = 0;
    if (t > 0) v = aload64(up);

    // ---- Phase A: bias + x-part + OWN-half h (local, from buf[t&1]) ----
    const unsigned short* hrow = &h_lds[t & 1][mb][0];
    floatx4 acc[4];
#pragma unroll
    for (int j = 0; j < 4; ++j)
      acc[j] = (floatx4){bias[j], bias[j], bias[j], bias[j]};
#pragma unroll
    for (int j = 0; j < 4; ++j)
      acc[j] = __builtin_amdgcn_mfma_f32_16x16x32_bf16(a0, wf[j][0],
                                                       acc[j], 0, 0, 0);
#pragma unroll
    for (int j = 0; j < 4; ++j)
      acc[j] = __builtin_amdgcn_mfma_f32_16x16x32_bf16(a1, wf[j][1],
                                                       acc[j], 0, 0, 0);
#pragma unroll
    for (int kk = 0; kk < 4; ++kk) {
      bf16x8 a = __builtin_bit_cast(
          bf16x8,
          *(const ushortx8*)(hrow + (kcO - 2 + kk) * 32 + lk * 8));
#pragma unroll
      for (int j = 0; j < 4; ++j)
        acc[j] = __builtin_amdgcn_mfma_f32_16x16x32_bf16(a, wf[j][kcO + kk],
                                                         acc[j], 0, 0, 0);
    }

    // ---- quiet pipelined poll for peer half of h_t ----
    if (t > 0) {
      bool ok = ((uint32)(v >> 32) == (uint32)t);
      int it = 0;
      while (!__all(ok) && ++it < SENT_CAP) {
        u64 n = 0;
        if (!ok) n = aload64(up);
        __builtin_amdgcn_s_sleep(1);
        if (!ok) {
          v = n;
          ok = ((uint32)(v >> 32) == (uint32)t);
        }
      }
      // capture payload into current read-buffer (peer cols, disjoint from
      // Phase A's own-col reads)
      *(uint32*)&h_lds[t & 1][pm][pcol] = (uint32)v;
    }
    __syncthreads();  // MID: peer half of buf[t&1] ready

    // ---- Phase C: peer-half h MFMAs (the only compute on the serial
    // publish->detect cycle) ----
#pragma unroll
    for (int kk = 0; kk < 4; ++kk) {
      bf16x8 a = __builtin_bit_cast(
          bf16x8,
          *(const ushortx8*)(hrow + (kcP - 2 + kk) * 32 + lk * 8));
#pragma unroll
      for (int j = 0; j < 4; ++j)
        acc[j] = __builtin_amdgcn_mfma_f32_16x16x32_bf16(a, wf[j][kcP + kk],
                                                         acc[j], 0, 0, 0);
    }

    // ---- in-register nonlinearity + c/h update; publish ASAP ----
    if (lk < 2) {
      floatx4 iv, fv, gv, ov;
#pragma unroll
      for (int r = 0; r < 4; ++r) {
        iv[r] = fast_sig(acc[0][r]);
        fv[r] = fast_sig(acc[1][r]);
        gv[r] = fast_tanh(acc[2][r]);
        ov[r] = fast_sig(acc[3][r]);
      }
      c_reg = fv * c_reg + iv * gv;
#pragma unroll
      for (int r = 0; r < 4; ++r) {
        float hv = ov[r] * fast_tanh(c_reg[r]);
        unsigned short hb = __builtin_bit_cast(unsigned short, (__bf16)hv);
        int pv = __shfl_xor((int)hb, 1);  // partner ln^1, same lk
        if ((ln & 1) == 0) {
          const int m = lk * 4 + r;
          uint32 dword = (uint32)hb | ((uint32)(unsigned short)pv << 16);
          u64 val = (u64)dword | ((u64)(uint32)(t + 1) << 32);
          const size_t uoff = obase + (size_t)m * 64 + ppair;
          if (t == T_ - 1) {
            // final h -> clean region (never polled, never RMW'd)
            astore64(units + 2 * (size_t)UNITS_PER_PARITY + uoff, val);
          } else {
            astore64(units + (size_t)((t + 1) & 1) * UNITS_PER_PARITY + uoff,
                     val);
            // own half -> next read-buffer
            *(uint32*)&h_lds[(t + 1) & 1][m][ocol] = dword;
          }
        }
      }
    }
    __syncthreads();  // END: buf[(t+1)&1] own half ready for Phase A(t+1)
  }
}

// out[b] = dot(h_T[b], fc_w) + fc_b. Final h lives in the clean region at
// offset 2*UPP. Agent loads -> fresh across replays, no flush dependency.
__global__ void lstm_fc(const u64* __restrict__ units,
                        const float* __restrict__ fc_w,
                        const float* __restrict__ fc_b,
                        float* __restrict__ out) {
  const int b = threadIdx.x;
  const int g = b >> 3, m = b & 7;
  const u64* base =
      units + 2 * (size_t)UNITS_PER_PARITY + (size_t)g * UNITS_PER_GROUP;
  float sum = fc_b[0];
#pragma unroll 4
  for (int u = 0; u < 128; ++u) {
    const int hf = u >> 6, pair = u & 63;
    u64 v = aload64(base + hf * 512 + m * 64 + pair);
    uint32 lo = (uint32)v;
    const int d = hf * HH + 2 * pair;
    sum += bf2f(lo & 0xffffu) * fc_w[d] + bf2f(lo >> 16) * fc_w[d + 1];
  }
  out[b] = sum;
}

extern "C" void kernel_launch(void* const* d_in, const int* in_sizes, int n_in,
                              void* d_out, int out_size, void* d_ws,
                              size_t ws_size, hipStream_t stream) {
  const float* x    = (const float*)d_in[0];
  const float* W_ih = (const float*)d_in[1];
  const float* W_hh = (const float*)d_in[2];
  const float* b_ih = (const float*)d_in[3];
  const float* b_hh = (const float*)d_in[4];
  const float* fc_w = (const float*)d_in[5];
  const float* fc_b = (const float*)d_in[6];
  float* out = (float*)d_out;

  u64* units = (u64*)d_ws;  // 2 parities + final region: 3*256KB = 768KB ws
  // tag poison 0xAAAAAAAA != any live tag (1..1024) => no init needed.

  lstm_main<<<dim3(NGROUP * 2), dim3(512), 0, stream>>>(
      x, W_ih, W_hh, b_ih, b_hh, units);
  lstm_fc<<<dim3(1), dim3(256), 0, stream>>>(units, fc_w, fc_b, out);
}

// Round 7
// 3471.259 us; speedup vs baseline: 2.8518x; 2.8518x over previous
//
#include <hip/hip_runtime.h>
#include <stdint.h>

// LSTM: B=256, T=1024, I=64, H=256, O=1. fp32 in/out, bf16 MFMA internally.
//
// Round-18 = R17 resubmitted verbatim (R17's bench never ran: GPU
// acquisition timeout). R17 = R16 structure with the rule-#20 fix. R16's
// VGPR_Count=80 proved the ENTIRE wf[4][10] array lived in scratch:
// wf[j][kcO+kk] used kcO = 2+half*4, a RUNTIME index (half = bid>>5), and
// runtime-indexed register arrays are demoted to local memory. (R15's
// spill was different: the (512,2) bound capped VGPRs at 128.) Fix:
// reorder fragment slots per block at LOAD time so all wf indices are
// compile-time:
//   slot 0..1 = x-part (W_ih)
//   slot 2..5 = OWN-half W_hh columns  (cols half*128   .. +127)
//   slot 6..9 = PEER-half W_hh columns (cols (half^1)*128 .. +127)
// The half-dependence moves into load ADDRESSES (ordinary runtime values);
// Phase A uses wf[j][2+kk], Phase C wf[j][6+kk] - static after unroll.
// A-fragments read h_lds at runtime col base ownb/peerb (LDS addressing is
// runtime anyway). __launch_bounds__(512,1) keeps the cap at 512.
//
// Topology (R15/R16): 64 blocks = 32 groups x 2 halves, 512 thr. Wave wv
// owns hid = half*128+wv*16+ln for ALL 4 gates -> c/h update in-register.
// Software-pipelined recurrence: Phase A (bias + x + own-half h: 24 MFMAs)
// runs while the peer poll is in flight; only Phase C (peer-half: 16
// MFMAs) + nonlin + publish sit on the serial publish->visibility->detect
// cycle. x prefetched one step ahead (clamped at T-1).
//
// Communication: R11/R13-verified relaxed AGENT-scope (MALL) 8B units
// {2xbf16 h pair, tag=step}; quiet pipelined poll (probe before sleep,
// reload issued BEFORE s_sleep(1), satisfied lanes stop loading, SENT_CAP
// dead-latch => wrong-answer-not-hang). Tag poison 0xAAAAAAAA != live tags
// 1..1024 => no ws init. Final h (tag 1024) -> separate never-polled clean
// region at 2*UPP (R13-verified). Parity/staleness argument as R15.
//
// LDS: h_lds[2][8][264] double buffer. iter t: Phase A reads OWN cols of
// buf[t&1] (written by update(t-1), ordered by END-barrier(t-1)); capture
// writes PEER cols of buf[t&1] (disjoint); MID-barrier; Phase C reads peer
// cols; update writes own h(t+1) to buf[(t+1)&1] + publishes; END-barrier.

#define T_ 1024
#define I_ 64
#define H_ 256
#define NGROUP 32
#define MB 8      /* batches per group  */
#define HH 128    /* hidden units per block (half) */
#define HROW 264  /* padded h_lds row (ushorts), 528 B = 33 x 16 B */

#define UNITS_PER_GROUP 1024                       /* 8B units per step */
#define UNITS_PER_PARITY (NGROUP * UNITS_PER_GROUP)
#define SENT_CAP (1 << 16)   /* dead-latch: ~64k sleep-sweeps */

typedef float floatx4 __attribute__((ext_vector_type(4)));
typedef __bf16 bf16x8 __attribute__((ext_vector_type(8)));
typedef unsigned short ushortx8 __attribute__((ext_vector_type(8)));
typedef unsigned int uint32;
typedef unsigned long long u64;

__device__ __forceinline__ float bf2f(uint32 u16) {
  uint32 u = u16 << 16;
  return __builtin_bit_cast(float, u);
}
__device__ __forceinline__ bf16x8 packbf8(floatx4 a, floatx4 b) {
  bf16x8 r;
  r[0] = (__bf16)a[0]; r[1] = (__bf16)a[1];
  r[2] = (__bf16)a[2]; r[3] = (__bf16)a[3];
  r[4] = (__bf16)b[0]; r[5] = (__bf16)b[1];
  r[6] = (__bf16)b[2]; r[7] = (__bf16)b[3];
  return r;
}
__device__ __forceinline__ float fast_sig(float v) {
  return 1.0f / (1.0f + __expf(-v));
}
__device__ __forceinline__ float fast_tanh(float v) {
  float e = __expf(2.0f * v);
  return 1.0f - 2.0f / (e + 1.0f);
}
__device__ __forceinline__ u64 aload64(const u64* p) {
  return __hip_atomic_load(p, __ATOMIC_RELAXED, __HIP_MEMORY_SCOPE_AGENT);
}
__device__ __forceinline__ void astore64(u64* p, u64 v) {
  __hip_atomic_store(p, v, __ATOMIC_RELAXED, __HIP_MEMORY_SCOPE_AGENT);
}

__global__ __launch_bounds__(512, 1) void lstm_main(
    const float* __restrict__ x, const float* __restrict__ W_ih,
    const float* __restrict__ W_hh, const float* __restrict__ b_ih,
    const float* __restrict__ b_hh, u64* __restrict__ units) {
  const int tid = threadIdx.x;
  const int bid = blockIdx.x;
  const int half = bid >> 5;  // 0..1
  const int g = bid & 31;     // group 0..31 (bid%8 spreads XCDs)
  const int wv = tid >> 6;    // wave 0..7 -> hid sub-block
  const int lane = tid & 63;
  const int ln = lane & 15;   // MFMA n (hid) / A row (batch, dup)
  const int lk = lane >> 4;   // MFMA k-subgroup / C row group

  __shared__ __align__(16) unsigned short h_lds[2][MB][HROW];

  const size_t gbase = (size_t)g * UNITS_PER_GROUP;
  const size_t obase = gbase + (size_t)half * 512;        // own units
  const size_t pbase = gbase + (size_t)(half ^ 1) * 512;  // peer units
  const int ownb = half * HH;                             // own col base
  const int peerb = (half ^ 1) * HH;                      // peer col base

  // zero both h_lds buffers (h_0 = 0; also clears pad)
  {
    uint32* p = (uint32*)&h_lds[0][0][0];
    for (int i = tid; i < 2 * MB * HROW / 2; i += 512) p[i] = 0u;
  }

  // ---- preload weight B-fragments (bf16) + bias, once ----
  // wave wv owns hid = half*128 + wv*16 + ln, ALL 4 gates (j).
  // Slot order: 0..1 x | 2..5 own-half W_hh | 6..9 peer-half W_hh.
  bf16x8 wf[4][10];
  float bias[4];
#pragma unroll
  for (int j = 0; j < 4; ++j) {
    const int row = j * 256 + half * HH + wv * 16 + ln;
    bias[j] = b_ih[row] + b_hh[row];
    const float* wih = W_ih + (size_t)row * I_;
    const float* whh = W_hh + (size_t)row * H_;
#pragma unroll
    for (int fc = 0; fc < 10; ++fc) {
      const float* src;
      if (fc < 2)      src = wih + fc * 32 + lk * 8;
      else if (fc < 6) src = whh + ownb + (fc - 2) * 32 + lk * 8;
      else             src = whh + peerb + (fc - 6) * 32 + lk * 8;
      floatx4 f0 = *(const floatx4*)src;
      floatx4 f1 = *(const floatx4*)(src + 4);
      wf[j][fc] = packbf8(f0, f1);
    }
  }

  const int mb = ln & 7;                       // batch row (m>=8 duplicates)
  const float* xrow = x + ((size_t)(g * MB + mb)) * T_ * I_;
  // poll roles: thread i <-> peer unit i
  const int pm = tid >> 6;                     // batch of polled unit
  const int pcol = peerb + 2 * (tid & 63);     // h_lds col (ushort)
  // publish roles: active lanes lk<2 && even ln; pair idx within half
  const int ppair = wv * 8 + (ln >> 1);
  const int ocol = ownb + wv * 16 + ln;        // own h_lds col (ushort)

  floatx4 c_reg = (floatx4){0.f, 0.f, 0.f, 0.f};

  // preload x_0
  floatx4 xf0, xf1, xf2, xf3;
  {
    const float* src = xrow + lk * 8;
    xf0 = *(const floatx4*)(src);
    xf1 = *(const floatx4*)(src + 4);
    xf2 = *(const floatx4*)(src + 32);
    xf3 = *(const floatx4*)(src + 36);
  }

  __syncthreads();

#pragma unroll 1
  for (int t = 0; t < T_; ++t) {
    // pack x_t fragments, then issue x_{t+1} prefetch (latency hides under
    // Phase A + poll)
    bf16x8 a0 = packbf8(xf0, xf1);
    bf16x8 a1 = packbf8(xf2, xf3);
    {
      const int tn = (t + 1 < T_) ? (t + 1) : t;
      const float* src = xrow + tn * I_ + lk * 8;
      xf0 = *(const floatx4*)(src);
      xf1 = *(const floatx4*)(src + 4);
      xf2 = *(const floatx4*)(src + 32);
      xf3 = *(const floatx4*)(src + 36);
    }

    // issue first poll probe BEFORE Phase A so it flies under the MFMAs
    u64* up = units + (size_t)(t & 1) * UNITS_PER_PARITY + pbase + tid;
    u64 v = 0;
    if (t > 0) v = aload64(up);

    // ---- Phase A: bias + x-part + OWN-half h (local, from buf[t&1]) ----
    const unsigned short* hrow = &h_lds[t & 1][mb][0];
    floatx4 acc[4];
#pragma unroll
    for (int j = 0; j < 4; ++j)
      acc[j] = (floatx4){bias[j], bias[j], bias[j], bias[j]};
#pragma unroll
    for (int j = 0; j < 4; ++j)
      acc[j] = __builtin_amdgcn_mfma_f32_16x16x32_bf16(a0, wf[j][0],
                                                       acc[j], 0, 0, 0);
#pragma unroll
    for (int j = 0; j < 4; ++j)
      acc[j] = __builtin_amdgcn_mfma_f32_16x16x32_bf16(a1, wf[j][1],
                                                       acc[j], 0, 0, 0);
#pragma unroll
    for (int kk = 0; kk < 4; ++kk) {
      bf16x8 a = __builtin_bit_cast(
          bf16x8, *(const ushortx8*)(hrow + ownb + kk * 32 + lk * 8));
#pragma unroll
      for (int j = 0; j < 4; ++j)
        acc[j] = __builtin_amdgcn_mfma_f32_16x16x32_bf16(a, wf[j][2 + kk],
                                                         acc[j], 0, 0, 0);
    }

    // ---- quiet pipelined poll for peer half of h_t ----
    if (t > 0) {
      bool ok = ((uint32)(v >> 32) == (uint32)t);
      int it = 0;
      while (!__all(ok) && ++it < SENT_CAP) {
        u64 n = 0;
        if (!ok) n = aload64(up);
        __builtin_amdgcn_s_sleep(1);
        if (!ok) {
          v = n;
          ok = ((uint32)(v >> 32) == (uint32)t);
        }
      }
      // capture payload into current read-buffer (peer cols, disjoint from
      // Phase A's own-col reads)
      *(uint32*)&h_lds[t & 1][pm][pcol] = (uint32)v;
    }
    __syncthreads();  // MID: peer half of buf[t&1] ready

    // ---- Phase C: peer-half h MFMAs (the only compute on the serial
    // publish->detect cycle) ----
#pragma unroll
    for (int kk = 0; kk < 4; ++kk) {
      bf16x8 a = __builtin_bit_cast(
          bf16x8, *(const ushortx8*)(hrow + peerb + kk * 32 + lk * 8));
#pragma unroll
      for (int j = 0; j < 4; ++j)
        acc[j] = __builtin_amdgcn_mfma_f32_16x16x32_bf16(a, wf[j][6 + kk],
                                                         acc[j], 0, 0, 0);
    }

    // ---- in-register nonlinearity + c/h update; publish ASAP ----
    if (lk < 2) {
      floatx4 iv, fv, gv, ov;
#pragma unroll
      for (int r = 0; r < 4; ++r) {
        iv[r] = fast_sig(acc[0][r]);
        fv[r] = fast_sig(acc[1][r]);
        gv[r] = fast_tanh(acc[2][r]);
        ov[r] = fast_sig(acc[3][r]);
      }
      c_reg = fv * c_reg + iv * gv;
#pragma unroll
      for (int r = 0; r < 4; ++r) {
        float hv = ov[r] * fast_tanh(c_reg[r]);
        unsigned short hb = __builtin_bit_cast(unsigned short, (__bf16)hv);
        int pv = __shfl_xor((int)hb, 1);  // partner ln^1, same lk
        if ((ln & 1) == 0) {
          const int m = lk * 4 + r;
          uint32 dword = (uint32)hb | ((uint32)(unsigned short)pv << 16);
          u64 val = (u64)dword | ((u64)(uint32)(t + 1) << 32);
          const size_t uoff = obase + (size_t)m * 64 + ppair;
          if (t == T_ - 1) {
            // final h -> clean region (never polled, never RMW'd)
            astore64(units + 2 * (size_t)UNITS_PER_PARITY + uoff, val);
          } else {
            astore64(units + (size_t)((t + 1) & 1) * UNITS_PER_PARITY + uoff,
                     val);
            // own half -> next read-buffer
            *(uint32*)&h_lds[(t + 1) & 1][m][ocol] = dword;
          }
        }
      }
    }
    __syncthreads();  // END: buf[(t+1)&1] own half ready for Phase A(t+1)
  }
}

// out[b] = dot(h_T[b], fc_w) + fc_b. Final h lives in the clean region at
// offset 2*UPP. Agent loads -> fresh across replays, no flush dependency.
__global__ void lstm_fc(const u64* __restrict__ units,
                        const float* __restrict__ fc_w,
                        const float* __restrict__ fc_b,
                        float* __restrict__ out) {
  const int b = threadIdx.x;
  const int g = b >> 3, m = b & 7;
  const u64* base =
      units + 2 * (size_t)UNITS_PER_PARITY + (size_t)g * UNITS_PER_GROUP;
  float sum = fc_b[0];
#pragma unroll 4
  for (int u = 0; u < 128; ++u) {
    const int hf = u >> 6, pair = u & 63;
    u64 v = aload64(base + hf * 512 + m * 64 + pair);
    uint32 lo = (uint32)v;
    const int d = hf * HH + 2 * pair;
    sum += bf2f(lo & 0xffffu) * fc_w[d] + bf2f(lo >> 16) * fc_w[d + 1];
  }
  out[b] = sum;
}

extern "C" void kernel_launch(void* const* d_in, const int* in_sizes, int n_in,
                              void* d_out, int out_size, void* d_ws,
                              size_t ws_size, hipStream_t stream) {
  const float* x    = (const float*)d_in[0];
  const float* W_ih = (const float*)d_in[1];
  const float* W_hh = (const float*)d_in[2];
  const float* b_ih = (const float*)d_in[3];
  const float* b_hh = (const float*)d_in[4];
  const float* fc_w = (const float*)d_in[5];
  const float* fc_b = (const float*)d_in[6];
  float* out = (float*)d_out;

  u64* units = (u64*)d_ws;  // 2 parities + final region: 3*256KB = 768KB ws
  // tag poison 0xAAAAAAAA != any live tag (1..1024) => no init needed.

  lstm_main<<<dim3(NGROUP * 2), dim3(512), 0, stream>>>(
      x, W_ih, W_hh, b_ih, b_hh, units);
  lstm_fc<<<dim3(1), dim3(256), 0, stream>>>(units, fc_w, fc_b, out);
}